// Round 10
// baseline (341.492 us; speedup 1.0000x reference)
//
#include <hip/hip_runtime.h>
#include <hip/hip_bf16.h>
#include <stdint.h>

// B=2, N=128, D=512, LAYERS=3.
// Algebraic reduction: the [B,N,N,*] concat-GEMMs decompose into rank terms.
// Only rel@Wgr_c (x2) + rel3@W_esa are big MFMA GEMMs; rel1 = tanh(A[i]+C[j]).
// Softmax over axis i without the max pass (|s|<=~23 << f32 exp overflow).
// Round-10 delta vs round-9 (252.5us): big GEMM restructured to 256x256 tile,
// 512 thr / 8 waves (2Mx4N, wave tile 128x64, acc 128 VGPR -> 2 waves/SIMD),
// 128KB double-buffered LDS, ONE __syncthreads per K-tile with next-tile
// staging issued during phases 0-1 of the current tile's compute (T3-minimum:
// stage-early + single drain, 2-3 phases of L2 cover).  Round-9 analysis:
// after T2 the GEMMs are LDS-volume-bound (2048 wave-ds_read_b128 x 12cy ~
// 10us/CU) -- 128x64 wave tiles cut frag-reads/MFMA from 1.0 to 0.75 and
// halve A-refetch (2 n0 blocks vs 4).  Same K-order per output element ->
// bit-identical results.  Kept: T2 XOR swizzle (r9, -10.7us), XCD swizzle
// (r5, -7.6us), rel1 folded into m3 (r8).

#define DEV static __device__ __forceinline__

typedef float  f32x4   __attribute__((ext_vector_type(4)));
typedef float  f32x16  __attribute__((ext_vector_type(16)));
typedef __bf16 bf16x8  __attribute__((ext_vector_type(8)));
typedef __bf16 bf16x4  __attribute__((ext_vector_type(4)));

DEV float tanh_fast(float x) {
  float e = __expf(2.0f * x);
  return 1.0f - 2.0f * __frcp_rn(e + 1.0f);
}

DEV void gl_lds16(const void* g, void* l) {
  __builtin_amdgcn_global_load_lds(
      (const __attribute__((address_space(1))) unsigned int*)g,
      (__attribute__((address_space(3))) unsigned int*)l, 16, 0, 0);
}

// swizzled LDS byte address for a [*, 64 bf16] row-major tile (128B rows)
DEV int swz(int row, int kbyte) { return row * 128 + (kbyte ^ ((row & 7) << 4)); }

// ------------- prep: weight transpose->bf16 hi/lo, x0 split, dvec ---------------
struct WC { const float* W; __bf16* Wh; __bf16* Wl; };
struct Prep {
  WC w[7];
  const float* x0; __bf16* x0h; __bf16* x0l;
  const float* b_rel; const float* Wgrc; const float* b_gr; float* dvec;
};

__global__ __launch_bounds__(256) void prep_kernel(Prep pp) {
  const int y = blockIdx.y;
  if (y < 7) {
    const WC wc = pp.w[y];
    __shared__ float tile[32][33];
    int t = threadIdx.x;
    int tx = t & 31, ty = t >> 5;                     // 32 x 8
    int bx = blockIdx.x & 15, by = blockIdx.x >> 4;   // 16 x 16 tiles of 32x32
    int k0 = by * 32, n0 = bx * 32;
#pragma unroll
    for (int r = 0; r < 4; ++r) {
      int k = ty + r * 8;
      tile[k][tx] = wc.W[(size_t)(k0 + k) * 512 + n0 + tx];
    }
    __syncthreads();
#pragma unroll
    for (int r = 0; r < 4; ++r) {
      int n = ty + r * 8;
      float v = tile[tx][n];
      __bf16 h = (__bf16)v;
      wc.Wh[(size_t)(n0 + n) * 512 + k0 + tx] = h;
      wc.Wl[(size_t)(n0 + n) * 512 + k0 + tx] = (__bf16)(v - (float)h);
    }
  } else if (y == 7) {
    int i = blockIdx.x * 256 + threadIdx.x;
    if (i < 32768) {
      float4 v = ((const float4*)pp.x0)[i];
      float vv[4] = {v.x, v.y, v.z, v.w};
      bf16x4 h, l;
#pragma unroll
      for (int e = 0; e < 4; ++e) {
        __bf16 he = (__bf16)vv[e];
        h[e] = he;
        l[e] = (__bf16)(vv[e] - (float)he);
      }
      ((bf16x4*)pp.x0h)[i] = h;
      ((bf16x4*)pp.x0l)[i] = l;
    }
  } else {
    if (blockIdx.x < 2) {
      int n = blockIdx.x * 256 + threadIdx.x;
      float acc = pp.b_gr[n];
#pragma unroll 8
      for (int k = 0; k < 512; ++k) acc += pp.b_rel[k] * pp.Wgrc[(size_t)k * 512 + n];
      pp.dvec[n] = acc;
    }
  }
}

// ------------- small MFMA GEMM batch: out = act(X@W + bias + add) ---------------
// M=256, N=512, K=512. 64x64 tiles, split-precision compensated bf16.
struct MOp {
  const __bf16* Xh; const __bf16* Xl;   // [256,512]
  const __bf16* Wh; const __bf16* Wl;   // [512(n),512(k)] transposed
  const float* bias;                    // [512] or null
  const float* add;                     // [256,512] or null
  float* outf;                          // [256,512] or null
  __bf16* outh; __bf16* outl;           // [256,512] or null
  int act;                              // 1 = tanh
};
struct MBatch { MOp op[5]; };

DEV void mfma_small_body(const MOp& o) {
  const int m0 = ((int)blockIdx.x >> 3) * 64;
  const int n0 = ((int)blockIdx.x & 7) * 64;
  __shared__ __bf16 Ah[64 * 64], Al[64 * 64], Bh[64 * 64], Bl[64 * 64];
  const int t = threadIdx.x, lane = t & 63, wave = t >> 6;
  const int waveM = wave >> 1, waveN = wave & 1;
  const bool comp = (o.Xl != nullptr);

  f32x4 vzero = {0.f, 0.f, 0.f, 0.f};
  f32x4 acc[2][2];
#pragma unroll
  for (int a = 0; a < 2; ++a)
#pragma unroll
    for (int c = 0; c < 2; ++c) acc[a][c] = vzero;

  const int lr = lane >> 3;
  const int lc = ((lane & 7) ^ lr) * 8;   // pre-swizzled source granule

  for (int k0 = 0; k0 < 512; k0 += 64) {
    __syncthreads();
#pragma unroll
    for (int r = 0; r < 2; ++r) {
      const int rb = r * 32 + wave * 8;
      gl_lds16(o.Xh + (size_t)(m0 + rb + lr) * 512 + k0 + lc, &Ah[rb * 64]);
      gl_lds16(o.Wh + (size_t)(n0 + rb + lr) * 512 + k0 + lc, &Bh[rb * 64]);
      if (comp) {
        gl_lds16(o.Xl + (size_t)(m0 + rb + lr) * 512 + k0 + lc, &Al[rb * 64]);
        gl_lds16(o.Wl + (size_t)(n0 + rb + lr) * 512 + k0 + lc, &Bl[rb * 64]);
      }
    }
    __syncthreads();
#pragma unroll
    for (int kk = 0; kk < 2; ++kk) {
      const int kb = kk * 64 + (lane >> 4) * 16;   // byte offset within row
      const int ml = lane & 15;
      bf16x8 ah[2], bh[2], al[2], bl[2];
#pragma unroll
      for (int tm = 0; tm < 2; ++tm)
        ah[tm] = *(const bf16x8*)((const char*)Ah + swz(waveM * 32 + tm * 16 + ml, kb));
#pragma unroll
      for (int tn = 0; tn < 2; ++tn)
        bh[tn] = *(const bf16x8*)((const char*)Bh + swz(waveN * 32 + tn * 16 + ml, kb));
      if (comp) {
#pragma unroll
        for (int tm = 0; tm < 2; ++tm)
          al[tm] = *(const bf16x8*)((const char*)Al + swz(waveM * 32 + tm * 16 + ml, kb));
#pragma unroll
        for (int tn = 0; tn < 2; ++tn)
          bl[tn] = *(const bf16x8*)((const char*)Bl + swz(waveN * 32 + tn * 16 + ml, kb));
      }
#pragma unroll
      for (int tm = 0; tm < 2; ++tm)
#pragma unroll
        for (int tn = 0; tn < 2; ++tn) {
          acc[tm][tn] = __builtin_amdgcn_mfma_f32_16x16x32_bf16(ah[tm], bh[tn], acc[tm][tn], 0, 0, 0);
          if (comp) {
            acc[tm][tn] = __builtin_amdgcn_mfma_f32_16x16x32_bf16(ah[tm], bl[tn], acc[tm][tn], 0, 0, 0);
            acc[tm][tn] = __builtin_amdgcn_mfma_f32_16x16x32_bf16(al[tm], bh[tn], acc[tm][tn], 0, 0, 0);
          }
        }
    }
  }

  const int quad = lane >> 4, cl = lane & 15;
#pragma unroll
  for (int tm = 0; tm < 2; ++tm) {
#pragma unroll
    for (int r = 0; r < 4; ++r) {
      const int row = m0 + waveM * 32 + tm * 16 + quad * 4 + r;
#pragma unroll
      for (int tn = 0; tn < 2; ++tn) {
        const int col = n0 + waveN * 32 + tn * 16 + cl;
        float v = acc[tm][tn][r];
        if (o.bias) v += o.bias[col];
        if (o.add) v += o.add[(size_t)row * 512 + col];
        if (o.act) v = tanh_fast(v);
        if (o.outf) o.outf[(size_t)row * 512 + col] = v;
        if (o.outh) {
          __bf16 h = (__bf16)v;
          o.outh[(size_t)row * 512 + col] = h;
          o.outl[(size_t)row * 512 + col] = (__bf16)(v - (float)h);
        }
      }
    }
  }
}

__global__ __launch_bounds__(256, 2) void mfma_small_kernel(MBatch batch) {
  mfma_small_body(batch.op[blockIdx.y]);
}

// rel1 element slice: R1[e..e+7] = tanh(A[bi]+C[b,j]) for vec8 unit u
DEV void rel1_unit(const float* __restrict__ A, const float* __restrict__ C,
                   __bf16* __restrict__ R1, size_t u) {
  size_t e = u * 8;
  int d = (int)(e & 511);
  int j = (int)((e >> 9) & 127);
  int bi = (int)(e >> 16);         // b*128 + i
  int b = bi >> 7;
  const float* ap = &A[(size_t)bi * 512 + d];
  const float* cp = &C[((size_t)(b * 128 + j)) * 512 + d];
  float av[8], cv[8];
  *(float4*)&av[0] = *(const float4*)ap;
  *(float4*)&av[4] = *(const float4*)(ap + 4);
  *(float4*)&cv[0] = *(const float4*)cp;
  *(float4*)&cv[4] = *(const float4*)(cp + 4);
  bf16x8 o;
#pragma unroll
  for (int k = 0; k < 8; ++k) o[k] = (__bf16)tanh_fast(av[k] + cv[k]);
  *(bf16x8*)&R1[e] = o;
}

// m3 batch (3 GEMM ops, y=0..2, x<32) + rel1 slice (y=3, x=0..255 grid-stride).
__global__ __launch_bounds__(256, 2) void m3_rel1_kernel(
    MBatch batch, const float* __restrict__ A, const float* __restrict__ C,
    __bf16* __restrict__ R1) {
  if (blockIdx.y == 3) {
    size_t base = (size_t)blockIdx.x * 256 + threadIdx.x;
#pragma unroll 1
    for (int it = 0; it < 32; ++it)
      rel1_unit(A, C, R1, base + (size_t)it * 65536);
    return;
  }
  if (blockIdx.x >= 32) return;
  mfma_small_body(batch.op[blockIdx.y]);
}

// ------------- big MFMA GEMM: [32768,512] @ Wt^T, K=512, 32x32x16 --------------
// 256x256 tile, 512 thr / 8 waves (2Mx4N), wave tile 128x64.  Double-buffered
// 128KB LDS, T2 swizzle both sides; next K-tile staged during phases 0-1 of
// the current tile's compute; ONE __syncthreads per K-tile (drains staging
// with 2-3 phases of cover + fences buffer reuse).
// MODE 1: out bf16 tanh(acc + P[i] + Q[j]);  MODE 2: out f32 (acc + bias)
// XCD swizzle: grid 256 (%8==0) -> blk=(bid&7)*32+(bid>>3).

template <int MODE>
__global__ __launch_bounds__(512, 2) void big_gemm_kernel(
    const __bf16* __restrict__ Ab, const __bf16* __restrict__ Wt,
    const float* __restrict__ P, const float* __restrict__ Q,
    const float* __restrict__ bias, __bf16* __restrict__ outb,
    float* __restrict__ outf) {
  __shared__ __bf16 As[2][256 * 64];
  __shared__ __bf16 Bs[2][256 * 64];
  const int t = threadIdx.x;
  const int lane = t & 63;
  const int wave = t >> 6;
  const int wm = wave >> 2, wn = wave & 3;
  const int bid = (int)blockIdx.x;
  const int blk = (bid & 7) * 32 + (bid >> 3);  // bijective XCD swizzle
  const int bm2 = blk >> 1;                     // 256-row group
  const int n0 = (blk & 1) * 256;
  const size_t r0 = (size_t)bm2 * 256;
  const int bi0 = bm2 * 2;                      // first (b*128+i) of this tile

  const int lr = lane >> 3;
  const int lc = ((lane & 7) ^ lr) * 8;   // pre-swizzled source granule

  // stage rows [wave*32+p*8, +8) of A and B for K-chunk k0 into buffer sel
  auto stage2 = [&](int k0, int sel, int p) {
    const int rowg = wave * 32 + p * 8;
    gl_lds16(Ab + (r0 + rowg + lr) * 512 + k0 + lc, &As[sel][rowg * 64]);
    gl_lds16(Wt + (size_t)(n0 + rowg + lr) * 512 + k0 + lc, &Bs[sel][rowg * 64]);
  };

  f32x16 acc[4][2];
#pragma unroll
  for (int a = 0; a < 4; ++a)
#pragma unroll
    for (int c = 0; c < 2; ++c) acc[a][c] = (f32x16)0.f;

#pragma unroll
  for (int p = 0; p < 4; ++p) stage2(0, 0, p);
  __syncthreads();   // T0 landed

  const int ml = lane & 31;
  const int klb = (lane >> 5) * 16;

#pragma unroll 1
  for (int kt = 0; kt < 8; ++kt) {
    const int sel = kt & 1;
#pragma unroll
    for (int ks = 0; ks < 4; ++ks) {
      if (kt < 7 && ks < 2) {        // stage next tile early (phases 0-1)
        stage2((kt + 1) * 64, sel ^ 1, ks * 2);
        stage2((kt + 1) * 64, sel ^ 1, ks * 2 + 1);
      }
      const int kb = ks * 32 + klb;
      bf16x8 af[4], bfr[2];
#pragma unroll
      for (int tm = 0; tm < 4; ++tm)
        af[tm] = *(const bf16x8*)((const char*)As[sel] + swz(wm * 128 + tm * 32 + ml, kb));
#pragma unroll
      for (int tn = 0; tn < 2; ++tn)
        bfr[tn] = *(const bf16x8*)((const char*)Bs[sel] + swz(wn * 64 + tn * 32 + ml, kb));
#pragma unroll
      for (int tm = 0; tm < 4; ++tm)
#pragma unroll
        for (int tn = 0; tn < 2; ++tn)
          acc[tm][tn] = __builtin_amdgcn_mfma_f32_32x32x16_bf16(af[tm], bfr[tn], acc[tm][tn], 0, 0, 0);
    }
    __syncthreads();  // next tile landed; reads of buf[sel] done before reuse
  }

  const int cl = lane & 31, lg = lane >> 5;
  const int bi = bi0 + wm;          // (b*128 + i) of this wave's 128 rows
  const int b = bi >> 7;
#pragma unroll
  for (int tn = 0; tn < 2; ++tn) {
    const int col = n0 + wn * 64 + tn * 32 + cl;
    float pv;
    if (MODE == 2) pv = bias[col];
    else pv = P[(size_t)bi * 512 + col];
#pragma unroll
    for (int tm = 0; tm < 4; ++tm) {
#pragma unroll
      for (int reg = 0; reg < 16; ++reg) {
        const int j = tm * 32 + (reg & 3) + 8 * (reg >> 2) + 4 * lg;  // 0..127
        const size_t grow = r0 + wm * 128 + j;
        float v = acc[tm][tn][reg] + pv;
        if (MODE == 2) {
          outf[grow * 512 + col] = v;
        } else {
          v += Q[((size_t)(b * 128 + j)) * 512 + col];
          outb[grow * 512 + col] = (__bf16)tanh_fast(v);
        }
      }
    }
  }
}

// ------------- softmax over axis i (no max pass: |s| bounded), then sum over j --
__global__ __launch_bounds__(256) void softmax_l_kernel(
    const float* __restrict__ S, float* __restrict__ Lb) {
  int idx = blockIdx.x * 256 + threadIdx.x;   // = (b*128 + j)*512 + d
  int d = idx & 511;
  int j = (idx >> 9) & 127;
  int b = idx >> 16;
  const float* p = S + ((size_t)b * 16384 + j) * 512 + d;  // i = 0
  float l = 0.f;
#pragma unroll 8
  for (int ii = 0; ii < 128; ++ii) l += __expf(p[(size_t)ii * 65536]);
  Lb[idx] = __frcp_rn(l);
}

__global__ __launch_bounds__(256) void softmax_out_kernel(
    const float* __restrict__ S, const float* __restrict__ Lb,
    float* __restrict__ outp) {
  int idx = blockIdx.x * 256 + threadIdx.x;   // = (b*128 + i)*512 + d
  int d = idx & 511;
  int i = (idx >> 9) & 127;
  int b = idx >> 16;
  const float* sp = S + ((size_t)(b * 128 + i)) * 65536 + d;  // j = 0
  const float* lp = Lb + (size_t)b * 65536 + d;
  float acc = 0.f;
#pragma unroll 8
  for (int jj = 0; jj < 128; ++jj) {
    float s = sp[(size_t)jj * 512];
    acc += __expf(s) * lp[(size_t)jj * 512] * s;
  }
  outp[idx] = acc;
}

// --------------------------------------------------------------------------------
extern "C" void kernel_launch(void* const* d_in, const int* in_sizes, int n_in,
                              void* d_out, int out_size, void* d_ws, size_t ws_size,
                              hipStream_t stream) {
  const float* x0    = (const float*)d_in[0];
  const float* W_rel = (const float*)d_in[1];
  const float* b_rel = (const float*)d_in[2];
  const float* W_go  = (const float*)d_in[3];
  const float* b_go  = (const float*)d_in[4];
  const float* W_gr  = (const float*)d_in[5];
  const float* b_gr  = (const float*)d_in[6];
  const float* W_esa = (const float*)d_in[7];
  const float* b_esa = (const float*)d_in[8];

  const float* Wrel_top = W_rel;
  const float* Wrel_bot = W_rel + 512 * 512;
  const float* Wgr_a = W_gr;
  const float* Wgr_b = W_gr + 512 * 512;
  const float* Wgr_c = W_gr + 2 * 512 * 512;

  char* ws = (char*)d_ws;
  size_t off = 0;
  auto alloc = [&](size_t bytes) -> void* {
    void* p = ws + off;
    off += (bytes + 255) & ~(size_t)255;
    return p;
  };
  const size_t NREL = 16777216ull;  // B*N*N*D
  float*  S  = (float*)alloc(NREL * 4);        // 64 MB
  __bf16* R1 = (__bf16*)alloc(NREL * 2);       // 32 MB
  __bf16* R2 = (__bf16*)alloc(NREL * 2);       // 32 MB
  float* p0t  = (float*)alloc(131072 * 4);
  float* q0t  = (float*)alloc(131072 * 4);
  float* Abuf = (float*)alloc(131072 * 4);
  float* Cbuf = (float*)alloc(131072 * 4);
  float* p1   = (float*)alloc(131072 * 4);
  float* q1   = (float*)alloc(131072 * 4);
  float* p2   = (float*)alloc(131072 * 4);
  float* q2   = (float*)alloc(131072 * 4);
  float* dvec = (float*)alloc(512 * 4);
  float* Lb   = (float*)alloc(131072 * 4);
  __bf16* x0h = (__bf16*)alloc(131072 * 2);
  __bf16* x0l = (__bf16*)alloc(131072 * 2);
  __bf16* x1h = (__bf16*)alloc(131072 * 2);
  __bf16* x1l = (__bf16*)alloc(131072 * 2);
  __bf16* x2h = (__bf16*)alloc(131072 * 2);
  __bf16* x2l = (__bf16*)alloc(131072 * 2);
  __bf16* u0h = (__bf16*)alloc(131072 * 2);
  __bf16* u0l = (__bf16*)alloc(131072 * 2);
  __bf16* v0h = (__bf16*)alloc(131072 * 2);
  __bf16* v0l = (__bf16*)alloc(131072 * 2);
  __bf16* Wgo_h = (__bf16*)alloc(262144 * 2);
  __bf16* Wgo_l = (__bf16*)alloc(262144 * 2);
  __bf16* Wrt_h = (__bf16*)alloc(262144 * 2);
  __bf16* Wrt_l = (__bf16*)alloc(262144 * 2);
  __bf16* Wrb_h = (__bf16*)alloc(262144 * 2);
  __bf16* Wrb_l = (__bf16*)alloc(262144 * 2);
  __bf16* Wga_h = (__bf16*)alloc(262144 * 2);
  __bf16* Wga_l = (__bf16*)alloc(262144 * 2);
  __bf16* Wgb_h = (__bf16*)alloc(262144 * 2);
  __bf16* Wgb_l = (__bf16*)alloc(262144 * 2);
  __bf16* Wgc_h = (__bf16*)alloc(262144 * 2);
  __bf16* Wgc_l = (__bf16*)alloc(262144 * 2);
  __bf16* Wes_h = (__bf16*)alloc(262144 * 2);
  __bf16* Wes_l = (__bf16*)alloc(262144 * 2);

  float* x3out  = (float*)d_out;             // output 0
  float* relout = (float*)d_out + 131072;    // output 1

  Prep pp;
  pp.w[0] = {W_go, Wgo_h, Wgo_l};
  pp.w[1] = {Wrel_top, Wrt_h, Wrt_l};
  pp.w[2] = {Wrel_bot, Wrb_h, Wrb_l};
  pp.w[3] = {Wgr_a, Wga_h, Wga_l};
  pp.w[4] = {Wgr_b, Wgb_h, Wgb_l};
  pp.w[5] = {Wgr_c, Wgc_h, Wgc_l};
  pp.w[6] = {W_esa, Wes_h, Wes_l};
  pp.x0 = x0; pp.x0h = x0h; pp.x0l = x0l;
  pp.b_rel = b_rel; pp.Wgrc = Wgr_c; pp.b_gr = b_gr; pp.dvec = dvec;
  prep_kernel<<<dim3(256, 9), 256, 0, stream>>>(pp);

  MBatch m1 = {};
  m1.op[0] = {x0h, x0l, Wgo_h, Wgo_l, b_go, nullptr, nullptr, x1h, x1l, 1};
  m1.op[1] = {x0h, x0l, Wrt_h, Wrt_l, nullptr, nullptr, nullptr, u0h, u0l, 0};
  m1.op[2] = {x0h, x0l, Wrb_h, Wrb_l, nullptr, nullptr, nullptr, v0h, v0l, 0};
  m1.op[3] = {x0h, x0l, Wga_h, Wga_l, nullptr, nullptr, p0t, nullptr, nullptr, 0};
  m1.op[4] = {x0h, x0l, Wgb_h, Wgb_l, nullptr, nullptr, q0t, nullptr, nullptr, 0};
  mfma_small_kernel<<<dim3(32, 5), 256, 0, stream>>>(m1);

  MBatch m2 = {};
  m2.op[0] = {x1h, x1l, Wgo_h, Wgo_l, b_go, nullptr, nullptr, x2h, x2l, 1};
  m2.op[1] = {u0h, u0l, Wgc_h, Wgc_l, dvec, p0t, Abuf, nullptr, nullptr, 0};
  m2.op[2] = {v0h, v0l, Wgc_h, Wgc_l, nullptr, q0t, Cbuf, nullptr, nullptr, 0};
  m2.op[3] = {x1h, x1l, Wga_h, Wga_l, b_gr, nullptr, p1, nullptr, nullptr, 0};
  m2.op[4] = {x1h, x1l, Wgb_h, Wgb_l, nullptr, nullptr, q1, nullptr, nullptr, 0};
  mfma_small_kernel<<<dim3(32, 5), 256, 0, stream>>>(m2);

  // m3 batch + rel1 fold: y=0..2 GEMM ops (x<32), y=3 rel1 (256 blocks)
  MBatch m3 = {};
  m3.op[0] = {x2h, x2l, Wgo_h, Wgo_l, b_go, nullptr, x3out, nullptr, nullptr, 1};
  m3.op[1] = {x2h, x2l, Wga_h, Wga_l, b_gr, nullptr, p2, nullptr, nullptr, 0};
  m3.op[2] = {x2h, x2l, Wgb_h, Wgb_l, nullptr, nullptr, q2, nullptr, nullptr, 0};
  m3_rel1_kernel<<<dim3(256, 4), 256, 0, stream>>>(m3, Abuf, Cbuf, R1);

  // rel2 = tanh(rel1@Wgr_c + p1[i] + q1[j])
  big_gemm_kernel<1><<<256, 512, 0, stream>>>(R1, Wgc_h, p1, q1, nullptr, R2, nullptr);
  // rel3 = tanh(rel2@Wgr_c + p2[i] + q2[j])
  big_gemm_kernel<1><<<256, 512, 0, stream>>>(R2, Wgc_h, p2, q2, nullptr, R1, nullptr);
  // S = rel3@W_esa + b_esa
  big_gemm_kernel<2><<<256, 512, 0, stream>>>(R1, Wes_h, nullptr, nullptr, b_esa, nullptr, S);

  softmax_l_kernel<<<512, 256, 0, stream>>>(S, Lb);
  softmax_out_kernel<<<512, 256, 0, stream>>>(S, Lb, relout);
}

// Round 11
// 254.409 us; speedup vs baseline: 1.3423x; 1.3423x over previous
//
#include <hip/hip_runtime.h>
#include <hip/hip_bf16.h>
#include <stdint.h>

// B=2, N=128, D=512, LAYERS=3.
// Algebraic reduction: the [B,N,N,*] concat-GEMMs decompose into rank terms.
// Only rel@Wgr_c (x2) + rel3@W_esa are big MFMA GEMMs; rel1 = tanh(A[i]+C[j]).
// Softmax over axis i without the max pass (|s|<=~23 << f32 exp overflow).
// Round-11 = round-9 (252.5us: T2 XOR bank-swizzle both GEMMs, XCD swizzle,
// rel1 folded into m3) + big_gemm occupancy 2->4 blocks/CU
// (__launch_bounds__(256,4); grid 1024 = exactly 4x256 CUs).  r10's 256x256
// restructure spilled its 128-reg accumulator and dropped to 1 block/CU
// (75-100us/GEMM, 21% occ) -> reverted; its counters proved the r9-structure
// GEMM is latency-bound (19% HBM, 8% MfmaUtil), so more resident blocks is
// the cheapest way to hide the per-K-step vmcnt(0)+barrier drain (m114
// wave-overlap).  VGPR cap at 4 blocks/CU = 128 = exactly what the kernel
// already uses -> no spill expected.  Bit-identical math throughout.

#define DEV static __device__ __forceinline__

typedef float  f32x4   __attribute__((ext_vector_type(4)));
typedef float  f32x16  __attribute__((ext_vector_type(16)));
typedef __bf16 bf16x8  __attribute__((ext_vector_type(8)));
typedef __bf16 bf16x4  __attribute__((ext_vector_type(4)));

DEV float tanh_fast(float x) {
  float e = __expf(2.0f * x);
  return 1.0f - 2.0f * __frcp_rn(e + 1.0f);
}

DEV void gl_lds16(const void* g, void* l) {
  __builtin_amdgcn_global_load_lds(
      (const __attribute__((address_space(1))) unsigned int*)g,
      (__attribute__((address_space(3))) unsigned int*)l, 16, 0, 0);
}

// swizzled LDS byte address for a [*, 64 bf16] row-major tile (128B rows)
DEV int swz(int row, int kbyte) { return row * 128 + (kbyte ^ ((row & 7) << 4)); }

// ------------- prep: weight transpose->bf16 hi/lo, x0 split, dvec ---------------
struct WC { const float* W; __bf16* Wh; __bf16* Wl; };
struct Prep {
  WC w[7];
  const float* x0; __bf16* x0h; __bf16* x0l;
  const float* b_rel; const float* Wgrc; const float* b_gr; float* dvec;
};

__global__ __launch_bounds__(256) void prep_kernel(Prep pp) {
  const int y = blockIdx.y;
  if (y < 7) {
    const WC wc = pp.w[y];
    __shared__ float tile[32][33];
    int t = threadIdx.x;
    int tx = t & 31, ty = t >> 5;                     // 32 x 8
    int bx = blockIdx.x & 15, by = blockIdx.x >> 4;   // 16 x 16 tiles of 32x32
    int k0 = by * 32, n0 = bx * 32;
#pragma unroll
    for (int r = 0; r < 4; ++r) {
      int k = ty + r * 8;
      tile[k][tx] = wc.W[(size_t)(k0 + k) * 512 + n0 + tx];
    }
    __syncthreads();
#pragma unroll
    for (int r = 0; r < 4; ++r) {
      int n = ty + r * 8;
      float v = tile[tx][n];
      __bf16 h = (__bf16)v;
      wc.Wh[(size_t)(n0 + n) * 512 + k0 + tx] = h;
      wc.Wl[(size_t)(n0 + n) * 512 + k0 + tx] = (__bf16)(v - (float)h);
    }
  } else if (y == 7) {
    int i = blockIdx.x * 256 + threadIdx.x;
    if (i < 32768) {
      float4 v = ((const float4*)pp.x0)[i];
      float vv[4] = {v.x, v.y, v.z, v.w};
      bf16x4 h, l;
#pragma unroll
      for (int e = 0; e < 4; ++e) {
        __bf16 he = (__bf16)vv[e];
        h[e] = he;
        l[e] = (__bf16)(vv[e] - (float)he);
      }
      ((bf16x4*)pp.x0h)[i] = h;
      ((bf16x4*)pp.x0l)[i] = l;
    }
  } else {
    if (blockIdx.x < 2) {
      int n = blockIdx.x * 256 + threadIdx.x;
      float acc = pp.b_gr[n];
#pragma unroll 8
      for (int k = 0; k < 512; ++k) acc += pp.b_rel[k] * pp.Wgrc[(size_t)k * 512 + n];
      pp.dvec[n] = acc;
    }
  }
}

// ------------- small MFMA GEMM batch: out = act(X@W + bias + add) ---------------
// M=256, N=512, K=512. 64x64 tiles, split-precision compensated bf16.
struct MOp {
  const __bf16* Xh; const __bf16* Xl;   // [256,512]
  const __bf16* Wh; const __bf16* Wl;   // [512(n),512(k)] transposed
  const float* bias;                    // [512] or null
  const float* add;                     // [256,512] or null
  float* outf;                          // [256,512] or null
  __bf16* outh; __bf16* outl;           // [256,512] or null
  int act;                              // 1 = tanh
};
struct MBatch { MOp op[5]; };

DEV void mfma_small_body(const MOp& o) {
  const int m0 = ((int)blockIdx.x >> 3) * 64;
  const int n0 = ((int)blockIdx.x & 7) * 64;
  __shared__ __bf16 Ah[64 * 64], Al[64 * 64], Bh[64 * 64], Bl[64 * 64];
  const int t = threadIdx.x, lane = t & 63, wave = t >> 6;
  const int waveM = wave >> 1, waveN = wave & 1;
  const bool comp = (o.Xl != nullptr);

  f32x4 vzero = {0.f, 0.f, 0.f, 0.f};
  f32x4 acc[2][2];
#pragma unroll
  for (int a = 0; a < 2; ++a)
#pragma unroll
    for (int c = 0; c < 2; ++c) acc[a][c] = vzero;

  const int lr = lane >> 3;
  const int lc = ((lane & 7) ^ lr) * 8;   // pre-swizzled source granule

  for (int k0 = 0; k0 < 512; k0 += 64) {
    __syncthreads();
#pragma unroll
    for (int r = 0; r < 2; ++r) {
      const int rb = r * 32 + wave * 8;
      gl_lds16(o.Xh + (size_t)(m0 + rb + lr) * 512 + k0 + lc, &Ah[rb * 64]);
      gl_lds16(o.Wh + (size_t)(n0 + rb + lr) * 512 + k0 + lc, &Bh[rb * 64]);
      if (comp) {
        gl_lds16(o.Xl + (size_t)(m0 + rb + lr) * 512 + k0 + lc, &Al[rb * 64]);
        gl_lds16(o.Wl + (size_t)(n0 + rb + lr) * 512 + k0 + lc, &Bl[rb * 64]);
      }
    }
    __syncthreads();
#pragma unroll
    for (int kk = 0; kk < 2; ++kk) {
      const int kb = kk * 64 + (lane >> 4) * 16;   // byte offset within row
      const int ml = lane & 15;
      bf16x8 ah[2], bh[2], al[2], bl[2];
#pragma unroll
      for (int tm = 0; tm < 2; ++tm)
        ah[tm] = *(const bf16x8*)((const char*)Ah + swz(waveM * 32 + tm * 16 + ml, kb));
#pragma unroll
      for (int tn = 0; tn < 2; ++tn)
        bh[tn] = *(const bf16x8*)((const char*)Bh + swz(waveN * 32 + tn * 16 + ml, kb));
      if (comp) {
#pragma unroll
        for (int tm = 0; tm < 2; ++tm)
          al[tm] = *(const bf16x8*)((const char*)Al + swz(waveM * 32 + tm * 16 + ml, kb));
#pragma unroll
        for (int tn = 0; tn < 2; ++tn)
          bl[tn] = *(const bf16x8*)((const char*)Bl + swz(waveN * 32 + tn * 16 + ml, kb));
      }
#pragma unroll
      for (int tm = 0; tm < 2; ++tm)
#pragma unroll
        for (int tn = 0; tn < 2; ++tn) {
          acc[tm][tn] = __builtin_amdgcn_mfma_f32_16x16x32_bf16(ah[tm], bh[tn], acc[tm][tn], 0, 0, 0);
          if (comp) {
            acc[tm][tn] = __builtin_amdgcn_mfma_f32_16x16x32_bf16(ah[tm], bl[tn], acc[tm][tn], 0, 0, 0);
            acc[tm][tn] = __builtin_amdgcn_mfma_f32_16x16x32_bf16(al[tm], bh[tn], acc[tm][tn], 0, 0, 0);
          }
        }
    }
  }

  const int quad = lane >> 4, cl = lane & 15;
#pragma unroll
  for (int tm = 0; tm < 2; ++tm) {
#pragma unroll
    for (int r = 0; r < 4; ++r) {
      const int row = m0 + waveM * 32 + tm * 16 + quad * 4 + r;
#pragma unroll
      for (int tn = 0; tn < 2; ++tn) {
        const int col = n0 + waveN * 32 + tn * 16 + cl;
        float v = acc[tm][tn][r];
        if (o.bias) v += o.bias[col];
        if (o.add) v += o.add[(size_t)row * 512 + col];
        if (o.act) v = tanh_fast(v);
        if (o.outf) o.outf[(size_t)row * 512 + col] = v;
        if (o.outh) {
          __bf16 h = (__bf16)v;
          o.outh[(size_t)row * 512 + col] = h;
          o.outl[(size_t)row * 512 + col] = (__bf16)(v - (float)h);
        }
      }
    }
  }
}

__global__ __launch_bounds__(256, 2) void mfma_small_kernel(MBatch batch) {
  mfma_small_body(batch.op[blockIdx.y]);
}

// rel1 element slice: R1[e..e+7] = tanh(A[bi]+C[b,j]) for vec8 unit u
DEV void rel1_unit(const float* __restrict__ A, const float* __restrict__ C,
                   __bf16* __restrict__ R1, size_t u) {
  size_t e = u * 8;
  int d = (int)(e & 511);
  int j = (int)((e >> 9) & 127);
  int bi = (int)(e >> 16);         // b*128 + i
  int b = bi >> 7;
  const float* ap = &A[(size_t)bi * 512 + d];
  const float* cp = &C[((size_t)(b * 128 + j)) * 512 + d];
  float av[8], cv[8];
  *(float4*)&av[0] = *(const float4*)ap;
  *(float4*)&av[4] = *(const float4*)(ap + 4);
  *(float4*)&cv[0] = *(const float4*)cp;
  *(float4*)&cv[4] = *(const float4*)(cp + 4);
  bf16x8 o;
#pragma unroll
  for (int k = 0; k < 8; ++k) o[k] = (__bf16)tanh_fast(av[k] + cv[k]);
  *(bf16x8*)&R1[e] = o;
}

// m3 batch (3 GEMM ops, y=0..2, x<32) + rel1 slice (y=3, x=0..255 grid-stride).
__global__ __launch_bounds__(256, 2) void m3_rel1_kernel(
    MBatch batch, const float* __restrict__ A, const float* __restrict__ C,
    __bf16* __restrict__ R1) {
  if (blockIdx.y == 3) {
    size_t base = (size_t)blockIdx.x * 256 + threadIdx.x;
#pragma unroll 1
    for (int it = 0; it < 32; ++it)
      rel1_unit(A, C, R1, base + (size_t)it * 65536);
    return;
  }
  if (blockIdx.x >= 32) return;
  mfma_small_body(batch.op[blockIdx.y]);
}

// ------------- big MFMA GEMM: [32768,512] @ Wt^T, K=512, 32x32x16 --------------
// MODE 1: out bf16 tanh(acc + P[i] + Q[j]);  MODE 2: out f32 (acc + bias)
// LDS: linear 128B rows, T2 XOR swizzle (read side + pre-swizzled source).
// XCD swizzle: grid 1024 (%8==0) -> blk=(d%8)*128+d/8.
// __launch_bounds__(256,4): 4 blocks/CU (32KB LDS each, VGPR cap 128 = usage)
// -- more resident blocks to hide the per-K-step barrier drain.
constexpr int BM = 128, BN = 128, BK = 64;

template <int MODE>
__global__ __launch_bounds__(256, 4) void big_gemm_kernel(
    const __bf16* __restrict__ Ab, const __bf16* __restrict__ Wt,
    const float* __restrict__ P, const float* __restrict__ Q,
    const float* __restrict__ bias, __bf16* __restrict__ outb,
    float* __restrict__ outf) {
  __shared__ __bf16 As[BM * BK];
  __shared__ __bf16 Bs[BN * BK];
  const int t = threadIdx.x;
  const int lane = t & 63;
  const int wave = t >> 6;
  const int blk = ((int)blockIdx.x & 7) * 128 + ((int)blockIdx.x >> 3);
  const int bm = blk >> 2;                      // (b*128 + i)
  const int n0 = (blk & 3) * BN;
  const size_t r0 = (size_t)bm * BM;
  const int b = bm >> 7;
  const int i = bm & 127;
  const int waveM = wave >> 1, waveN = wave & 1;

  const int lr = lane >> 3;
  const int lc = ((lane & 7) ^ lr) * 8;   // pre-swizzled source granule

  f32x16 acc[2][2];
#pragma unroll
  for (int a = 0; a < 2; ++a)
#pragma unroll
    for (int c = 0; c < 2; ++c) acc[a][c] = (f32x16)0.f;

  for (int k0 = 0; k0 < 512; k0 += BK) {
    __syncthreads();
#pragma unroll
    for (int p2 = 0; p2 < 4; ++p2) {
      int rowg = wave * 32 + p2 * 8;
      const __bf16* ga = Ab + (r0 + rowg + lr) * 512 + k0 + lc;
      gl_lds16(ga, &As[rowg * 64]);
      const __bf16* gb = Wt + (size_t)(n0 + rowg + lr) * 512 + k0 + lc;
      gl_lds16(gb, &Bs[rowg * 64]);
    }
    __syncthreads();
    const int ml = lane & 31;
    const int klb = (lane >> 5) * 16;           // byte
#pragma unroll
    for (int ks = 0; ks < 4; ++ks) {
      const int kb = ks * 32 + klb;             // byte offset within row
      bf16x8 af[2], bfr[2];
#pragma unroll
      for (int tm = 0; tm < 2; ++tm)
        af[tm] = *(const bf16x8*)((const char*)As + swz(waveM * 64 + tm * 32 + ml, kb));
#pragma unroll
      for (int tn = 0; tn < 2; ++tn)
        bfr[tn] = *(const bf16x8*)((const char*)Bs + swz(waveN * 64 + tn * 32 + ml, kb));
#pragma unroll
      for (int tm = 0; tm < 2; ++tm)
#pragma unroll
        for (int tn = 0; tn < 2; ++tn)
          acc[tm][tn] = __builtin_amdgcn_mfma_f32_32x32x16_bf16(af[tm], bfr[tn], acc[tm][tn], 0, 0, 0);
    }
  }

  const int cl = lane & 31, lg = lane >> 5;
#pragma unroll
  for (int tm = 0; tm < 2; ++tm) {
#pragma unroll
    for (int tn = 0; tn < 2; ++tn) {
      const int col = n0 + waveN * 64 + tn * 32 + cl;
      float pv;
      if (MODE == 2) pv = bias[col];
      else pv = P[((size_t)(b * 128 + i)) * 512 + col];
#pragma unroll
      for (int reg = 0; reg < 16; ++reg) {
        const int row = waveM * 64 + tm * 32 + (reg & 3) + 8 * (reg >> 2) + 4 * lg;  // j
        float v = acc[tm][tn][reg] + pv;
        if (MODE == 2) {
          outf[(r0 + row) * 512 + col] = v;
        } else {
          v += Q[((size_t)(b * 128 + row)) * 512 + col];
          outb[(r0 + row) * 512 + col] = (__bf16)tanh_fast(v);
        }
      }
    }
  }
}

// ------------- softmax over axis i (no max pass: |s| bounded), then sum over j --
__global__ __launch_bounds__(256) void softmax_l_kernel(
    const float* __restrict__ S, float* __restrict__ Lb) {
  int idx = blockIdx.x * 256 + threadIdx.x;   // = (b*128 + j)*512 + d
  int d = idx & 511;
  int j = (idx >> 9) & 127;
  int b = idx >> 16;
  const float* p = S + ((size_t)b * 16384 + j) * 512 + d;  // i = 0
  float l = 0.f;
#pragma unroll 8
  for (int ii = 0; ii < 128; ++ii) l += __expf(p[(size_t)ii * 65536]);
  Lb[idx] = __frcp_rn(l);
}

__global__ __launch_bounds__(256) void softmax_out_kernel(
    const float* __restrict__ S, const float* __restrict__ Lb,
    float* __restrict__ outp) {
  int idx = blockIdx.x * 256 + threadIdx.x;   // = (b*128 + i)*512 + d
  int d = idx & 511;
  int i = (idx >> 9) & 127;
  int b = idx >> 16;
  const float* sp = S + ((size_t)(b * 128 + i)) * 65536 + d;  // j = 0
  const float* lp = Lb + (size_t)b * 65536 + d;
  float acc = 0.f;
#pragma unroll 8
  for (int jj = 0; jj < 128; ++jj) {
    float s = sp[(size_t)jj * 512];
    acc += __expf(s) * lp[(size_t)jj * 512] * s;
  }
  outp[idx] = acc;
}

// --------------------------------------------------------------------------------
extern "C" void kernel_launch(void* const* d_in, const int* in_sizes, int n_in,
                              void* d_out, int out_size, void* d_ws, size_t ws_size,
                              hipStream_t stream) {
  const float* x0    = (const float*)d_in[0];
  const float* W_rel = (const float*)d_in[1];
  const float* b_rel = (const float*)d_in[2];
  const float* W_go  = (const float*)d_in[3];
  const float* b_go  = (const float*)d_in[4];
  const float* W_gr  = (const float*)d_in[5];
  const float* b_gr  = (const float*)d_in[6];
  const float* W_esa = (const float*)d_in[7];
  const float* b_esa = (const float*)d_in[8];

  const float* Wrel_top = W_rel;
  const float* Wrel_bot = W_rel + 512 * 512;
  const float* Wgr_a = W_gr;
  const float* Wgr_b = W_gr + 512 * 512;
  const float* Wgr_c = W_gr + 2 * 512 * 512;

  char* ws = (char*)d_ws;
  size_t off = 0;
  auto alloc = [&](size_t bytes) -> void* {
    void* p = ws + off;
    off += (bytes + 255) & ~(size_t)255;
    return p;
  };
  const size_t NREL = 16777216ull;  // B*N*N*D
  float*  S  = (float*)alloc(NREL * 4);        // 64 MB
  __bf16* R1 = (__bf16*)alloc(NREL * 2);       // 32 MB
  __bf16* R2 = (__bf16*)alloc(NREL * 2);       // 32 MB
  float* p0t  = (float*)alloc(131072 * 4);
  float* q0t  = (float*)alloc(131072 * 4);
  float* Abuf = (float*)alloc(131072 * 4);
  float* Cbuf = (float*)alloc(131072 * 4);
  float* p1   = (float*)alloc(131072 * 4);
  float* q1   = (float*)alloc(131072 * 4);
  float* p2   = (float*)alloc(131072 * 4);
  float* q2   = (float*)alloc(131072 * 4);
  float* dvec = (float*)alloc(512 * 4);
  float* Lb   = (float*)alloc(131072 * 4);
  __bf16* x0h = (__bf16*)alloc(131072 * 2);
  __bf16* x0l = (__bf16*)alloc(131072 * 2);
  __bf16* x1h = (__bf16*)alloc(131072 * 2);
  __bf16* x1l = (__bf16*)alloc(131072 * 2);
  __bf16* x2h = (__bf16*)alloc(131072 * 2);
  __bf16* x2l = (__bf16*)alloc(131072 * 2);
  __bf16* u0h = (__bf16*)alloc(131072 * 2);
  __bf16* u0l = (__bf16*)alloc(131072 * 2);
  __bf16* v0h = (__bf16*)alloc(131072 * 2);
  __bf16* v0l = (__bf16*)alloc(131072 * 2);
  __bf16* Wgo_h = (__bf16*)alloc(262144 * 2);
  __bf16* Wgo_l = (__bf16*)alloc(262144 * 2);
  __bf16* Wrt_h = (__bf16*)alloc(262144 * 2);
  __bf16* Wrt_l = (__bf16*)alloc(262144 * 2);
  __bf16* Wrb_h = (__bf16*)alloc(262144 * 2);
  __bf16* Wrb_l = (__bf16*)alloc(262144 * 2);
  __bf16* Wga_h = (__bf16*)alloc(262144 * 2);
  __bf16* Wga_l = (__bf16*)alloc(262144 * 2);
  __bf16* Wgb_h = (__bf16*)alloc(262144 * 2);
  __bf16* Wgb_l = (__bf16*)alloc(262144 * 2);
  __bf16* Wgc_h = (__bf16*)alloc(262144 * 2);
  __bf16* Wgc_l = (__bf16*)alloc(262144 * 2);
  __bf16* Wes_h = (__bf16*)alloc(262144 * 2);
  __bf16* Wes_l = (__bf16*)alloc(262144 * 2);

  float* x3out  = (float*)d_out;             // output 0
  float* relout = (float*)d_out + 131072;    // output 1

  Prep pp;
  pp.w[0] = {W_go, Wgo_h, Wgo_l};
  pp.w[1] = {Wrel_top, Wrt_h, Wrt_l};
  pp.w[2] = {Wrel_bot, Wrb_h, Wrb_l};
  pp.w[3] = {Wgr_a, Wga_h, Wga_l};
  pp.w[4] = {Wgr_b, Wgb_h, Wgb_l};
  pp.w[5] = {Wgr_c, Wgc_h, Wgc_l};
  pp.w[6] = {W_esa, Wes_h, Wes_l};
  pp.x0 = x0; pp.x0h = x0h; pp.x0l = x0l;
  pp.b_rel = b_rel; pp.Wgrc = Wgr_c; pp.b_gr = b_gr; pp.dvec = dvec;
  prep_kernel<<<dim3(256, 9), 256, 0, stream>>>(pp);

  MBatch m1 = {};
  m1.op[0] = {x0h, x0l, Wgo_h, Wgo_l, b_go, nullptr, nullptr, x1h, x1l, 1};
  m1.op[1] = {x0h, x0l, Wrt_h, Wrt_l, nullptr, nullptr, nullptr, u0h, u0l, 0};
  m1.op[2] = {x0h, x0l, Wrb_h, Wrb_l, nullptr, nullptr, nullptr, v0h, v0l, 0};
  m1.op[3] = {x0h, x0l, Wga_h, Wga_l, nullptr, nullptr, p0t, nullptr, nullptr, 0};
  m1.op[4] = {x0h, x0l, Wgb_h, Wgb_l, nullptr, nullptr, q0t, nullptr, nullptr, 0};
  mfma_small_kernel<<<dim3(32, 5), 256, 0, stream>>>(m1);

  MBatch m2 = {};
  m2.op[0] = {x1h, x1l, Wgo_h, Wgo_l, b_go, nullptr, nullptr, x2h, x2l, 1};
  m2.op[1] = {u0h, u0l, Wgc_h, Wgc_l, dvec, p0t, Abuf, nullptr, nullptr, 0};
  m2.op[2] = {v0h, v0l, Wgc_h, Wgc_l, nullptr, q0t, Cbuf, nullptr, nullptr, 0};
  m2.op[3] = {x1h, x1l, Wga_h, Wga_l, b_gr, nullptr, p1, nullptr, nullptr, 0};
  m2.op[4] = {x1h, x1l, Wgb_h, Wgb_l, nullptr, nullptr, q1, nullptr, nullptr, 0};
  mfma_small_kernel<<<dim3(32, 5), 256, 0, stream>>>(m2);

  // m3 batch + rel1 fold: y=0..2 GEMM ops (x<32), y=3 rel1 (256 blocks)
  MBatch m3 = {};
  m3.op[0] = {x2h, x2l, Wgo_h, Wgo_l, b_go, nullptr, x3out, nullptr, nullptr, 1};
  m3.op[1] = {x2h, x2l, Wga_h, Wga_l, b_gr, nullptr, p2, nullptr, nullptr, 0};
  m3.op[2] = {x2h, x2l, Wgb_h, Wgb_l, nullptr, nullptr, q2, nullptr, nullptr, 0};
  m3_rel1_kernel<<<dim3(256, 4), 256, 0, stream>>>(m3, Abuf, Cbuf, R1);

  // rel2 = tanh(rel1@Wgr_c + p1[i] + q1[j])
  big_gemm_kernel<1><<<1024, 256, 0, stream>>>(R1, Wgc_h, p1, q1, nullptr, R2, nullptr);
  // rel3 = tanh(rel2@Wgr_c + p2[i] + q2[j])
  big_gemm_kernel<1><<<1024, 256, 0, stream>>>(R2, Wgc_h, p2, q2, nullptr, R1, nullptr);
  // S = rel3@W_esa + b_esa
  big_gemm_kernel<2><<<1024, 256, 0, stream>>>(R1, Wes_h, nullptr, nullptr, b_esa, nullptr, S);

  softmax_l_kernel<<<512, 256, 0, stream>>>(S, Lb);
  softmax_out_kernel<<<512, 256, 0, stream>>>(S, Lb, relout);
}